// Round 1
// 711.168 us; speedup vs baseline: 1.1780x; 1.1780x over previous
//
#include <hip/hip_runtime.h>
#include <stdint.h>

#define B_    2
#define S_    2048
#define H_    4096
#define NH_   32
#define NKV_  2
#define HD_   128
#define ROT_  64
#define QKVD  4608          // (NH + 2*NKV) * HD
#define MROWS 4096          // B*S

typedef __attribute__((ext_vector_type(8))) __bf16 bf16x8;
typedef __attribute__((ext_vector_type(4))) float f32x4;

__device__ __forceinline__ unsigned short f2bf(float f) {
    union { float f; unsigned u; } c; c.f = f;
    unsigned u = c.u;
    u += 0x7fffu + ((u >> 16) & 1u);          // round-to-nearest-even
    return (unsigned short)(u >> 16);
}

__device__ __forceinline__ void gload_lds16(const void* g, void* l) {
    __builtin_amdgcn_global_load_lds(
        (__attribute__((address_space(1))) void*)g,
        (__attribute__((address_space(3))) void*)l, 16, 0, 0);
}

// ---------------- prep: fp32 -> bf16 straight copy ----------------
__global__ __launch_bounds__(256) void convert_bf16(const float* __restrict__ src,
                                                    unsigned short* __restrict__ dst,
                                                    int n4) {
    int i = blockIdx.x * 256 + threadIdx.x;
    if (i < n4) {
        f32x4 v = ((const f32x4*)src)[i];
        ushort4 o;
        o.x = f2bf(v[0]); o.y = f2bf(v[1]); o.z = f2bf(v[2]); o.w = f2bf(v[3]);
        ((ushort4*)dst)[i] = o;
    }
}

// ---------------- prep: fp32 [K][N] -> bf16 [N][K] transpose ----------------
__global__ __launch_bounds__(256) void transpose_bf16(const float* __restrict__ src,
                                                      unsigned short* __restrict__ dst,
                                                      int K, int N) {
    __shared__ float tile[32][33];
    int n0 = blockIdx.x * 32, k0 = blockIdx.y * 32;
    int tx = threadIdx.x & 31, ty = threadIdx.x >> 5;   // ty: 0..7
#pragma unroll
    for (int i = 0; i < 4; i++)
        tile[ty + i * 8][tx] = src[(size_t)(k0 + ty + i * 8) * N + n0 + tx];
    __syncthreads();
#pragma unroll
    for (int i = 0; i < 4; i++)
        dst[(size_t)(n0 + ty + i * 8) * K + k0 + tx] = f2bf(tile[tx][ty + i * 8]);
}

// =================== 256x256 8-phase GEMM (T2+T3+T4+T5) ===================
// A [M][4096] bf16 row-major, BT [N][4096] bf16 row-major (B transposed).
// 512 thr = 8 waves (2M x 4N), per-wave 128x64 out, BK=64, 2 K-tiles/iter.
// LDS: 8 half-tile slots x 16KB = 128KB.
//   A slots (ushort off): (par*2+half)*8192          par = ktile&1
//   B slots             : 32768 + (par*2+half)*8192
// Swizzle: data for 16B-chunk (row, c) lives at LDS chunk (row, c^(row&7));
//   global_load_lds dest stays LINEAR, global source column pre-swizzled.

__device__ __forceinline__ void stage_half(const unsigned short* g,
                                           unsigned short* slot,
                                           int kt, int tid, int wave) {
    int ko = (kt < 64 ? kt : 63) << 6;      // clamp (tail dummy reads keep vmcnt math)
#pragma unroll
    for (int j = 0; j < 2; j++) {
        int li = j * 512 + tid;
        int r = li >> 3, s = li & 7;
        gload_lds16(g + ((size_t)r << 12) + ko + ((s ^ (r & 7)) << 3),
                    slot + (size_t)(j * 512 + wave * 64) * 8);
    }
}

template <int PAR, int MH>
__device__ __forceinline__ void lda_frags(const unsigned short* lds, bf16x8 (&af)[4][2],
                                          int wm, int lrow, int quad, int lw) {
    const unsigned short* p = lds + (PAR * 2 + MH) * 8192 + (wm * 64 + lrow) * 64;
#pragma unroll
    for (int mf = 0; mf < 4; mf++)
#pragma unroll
        for (int ks = 0; ks < 2; ks++)
            af[mf][ks] = *(const bf16x8*)(p + mf * 1024 + (((ks * 4 + quad) ^ lw) << 3));
}

template <int PAR, int NH>
__device__ __forceinline__ void ldb_frags(const unsigned short* lds, bf16x8 (&bf)[2][2],
                                          int wn, int lrow, int quad, int lw) {
    const unsigned short* p =
        lds + 32768 + (PAR * 2 + NH) * 8192 + (wn * 32 + lrow) * 64;
#pragma unroll
    for (int nf = 0; nf < 2; nf++)
#pragma unroll
        for (int ks = 0; ks < 2; ks++)
            bf[nf][ks] = *(const bf16x8*)(p + nf * 1024 + (((ks * 4 + quad) ^ lw) << 3));
}

template <int MH, int NH>
__device__ __forceinline__ void mfma_quad(f32x4 (&acc)[8][4], const bf16x8 (&af)[4][2],
                                          const bf16x8 (&bf)[2][2]) {
#pragma unroll
    for (int mf = 0; mf < 4; mf++)
#pragma unroll
        for (int nf = 0; nf < 2; nf++)
#pragma unroll
            for (int ks = 0; ks < 2; ks++)
                acc[MH * 4 + mf][NH * 2 + nf] = __builtin_amdgcn_mfma_f32_16x16x32_bf16(
                    af[mf][ks], bf[nf][ks], acc[MH * 4 + mf][NH * 2 + nf], 0, 0, 0);
}

#define MMPH(MH, NH, BF)                                   \
    __builtin_amdgcn_s_barrier();                          \
    asm volatile("s_waitcnt lgkmcnt(0)" ::: "memory");     \
    __builtin_amdgcn_s_setprio(1);                         \
    mfma_quad<MH, NH>(acc, af, BF);                        \
    __builtin_amdgcn_s_setprio(0);

// EPI 0: C fp32 [M][N], no bias (output projection)
// EPI 1: fused bias + RoPE + Q/K/V pack (N = 4608, n-col -> head/dcol)
template <int EPI, int N>
__global__ __launch_bounds__(512, 2) void gemm256(const unsigned short* __restrict__ A,
                                                  const unsigned short* __restrict__ BT,
                                                  const float* __restrict__ bias,
                                                  float* __restrict__ C,
                                                  unsigned short* __restrict__ Qb,
                                                  unsigned short* __restrict__ Kb,
                                                  unsigned short* __restrict__ Vb) {
    extern __shared__ unsigned short lds[];
    const int tid = threadIdx.x;
    const int lane = tid & 63, wave = tid >> 6;
    const int wm = wave >> 2, wn = wave & 3;           // 2 x 4 wave grid
    const int quad = lane >> 4, lrow = lane & 15, lw = lrow & 7;
    const int m0 = blockIdx.y * 256, n0 = blockIdx.x * 256;
    const unsigned short* gA0 = A + ((size_t)m0 << 12);
    const unsigned short* gA1 = gA0 + ((size_t)128 << 12);
    const unsigned short* gB0 = BT + ((size_t)n0 << 12);
    const unsigned short* gB1 = gB0 + ((size_t)128 << 12);

    f32x4 acc[8][4];
#pragma unroll
    for (int i = 0; i < 8; i++)
#pragma unroll
        for (int j = 0; j < 4; j++) acc[i][j] = (f32x4){0.f, 0.f, 0.f, 0.f};
    bf16x8 af[4][2], bf0[2][2], bf1[2][2];

    // prologue: A0(0) B0(0) A1(0) B1(0) A0(1) B0(1); leave last 2 halves in flight
    stage_half(gA0, lds,                 0, tid, wave);
    stage_half(gB0, lds + 32768,         0, tid, wave);
    stage_half(gA1, lds + 8192,          0, tid, wave);
    stage_half(gB1, lds + 32768 + 8192,  0, tid, wave);
    stage_half(gA0, lds + 16384,         1, tid, wave);
    stage_half(gB0, lds + 32768 + 16384, 1, tid, wave);
    asm volatile("s_waitcnt vmcnt(4)" ::: "memory");
    __builtin_amdgcn_s_barrier();

#pragma unroll 1
    for (int i = 0; i < 32; ++i) {
        const int t0 = 2 * i;
        // ---- K-tile t0 (par 0) ----
        // ph0: quad(0,0)   stage A1(t0+1) -> slot A[1][1]
        lda_frags<0, 0>(lds, af, wm, lrow, quad, lw);
        ldb_frags<0, 0>(lds, bf0, wn, lrow, quad, lw);
        stage_half(gA1, lds + 24576, t0 + 1, tid, wave);
        MMPH(0, 0, bf0);
        __builtin_amdgcn_s_barrier();
        // ph1: quad(0,1)   stage B1(t0+1)
        ldb_frags<0, 1>(lds, bf1, wn, lrow, quad, lw);
        stage_half(gB1, lds + 32768 + 24576, t0 + 1, tid, wave);
        MMPH(0, 1, bf1);
        __builtin_amdgcn_s_barrier();
        // ph2: quad(1,0)   stage A0(t0+2) -> slot A[0][0] (freed after ph0)
        lda_frags<0, 1>(lds, af, wm, lrow, quad, lw);
        stage_half(gA0, lds, t0 + 2, tid, wave);
        MMPH(1, 0, bf0);
        __builtin_amdgcn_s_barrier();
        // ph3: quad(1,1)   stage B0(t0+2); gate: t1 fully resident
        stage_half(gB0, lds + 32768, t0 + 2, tid, wave);
        MMPH(1, 1, bf1);
        asm volatile("s_waitcnt vmcnt(4)" ::: "memory");
        __builtin_amdgcn_s_barrier();
        // ---- K-tile t1 = t0+1 (par 1) ----
        // ph4: quad(0,0)   stage A1(t0+2) -> slot A[0][1] (freed after ph2)
        lda_frags<1, 0>(lds, af, wm, lrow, quad, lw);
        ldb_frags<1, 0>(lds, bf0, wn, lrow, quad, lw);
        stage_half(gA1, lds + 8192, t0 + 2, tid, wave);
        MMPH(0, 0, bf0);
        __builtin_amdgcn_s_barrier();
        // ph5: quad(0,1)   stage B1(t0+2)
        ldb_frags<1, 1>(lds, bf1, wn, lrow, quad, lw);
        stage_half(gB1, lds + 32768 + 8192, t0 + 2, tid, wave);
        MMPH(0, 1, bf1);
        __builtin_amdgcn_s_barrier();
        // ph6: quad(1,0)   stage A0(t0+3) -> slot A[1][0] (freed after ph4)
        lda_frags<1, 1>(lds, af, wm, lrow, quad, lw);
        stage_half(gA0, lds + 16384, t0 + 3, tid, wave);
        MMPH(1, 0, bf0);
        __builtin_amdgcn_s_barrier();
        // ph7: quad(1,1)   stage B0(t0+3); gate: tile t0+2 fully resident
        stage_half(gB0, lds + 32768 + 16384, t0 + 3, tid, wave);
        MMPH(1, 1, bf1);
        asm volatile("s_waitcnt vmcnt(4)" ::: "memory");
        __builtin_amdgcn_s_barrier();
    }

    if constexpr (EPI == 0) {
#pragma unroll
        for (int mh = 0; mh < 2; mh++)
#pragma unroll
            for (int mf = 0; mf < 4; mf++) {
                int gm = m0 + mh * 128 + wm * 64 + mf * 16 + quad * 4;
#pragma unroll
                for (int nh = 0; nh < 2; nh++)
#pragma unroll
                    for (int nf = 0; nf < 2; nf++) {
                        int gn = n0 + nh * 128 + wn * 32 + nf * 16 + lrow;
#pragma unroll
                        for (int r = 0; r < 4; r++)
                            C[(size_t)(gm + r) * N + gn] = acc[mh * 4 + mf][nh * 2 + nf][r];
                    }
            }
    } else {
        const float QSCALE = 0.08838834764831843f * 1.4426950408889634f;
#pragma unroll
        for (int mh = 0; mh < 2; mh++)
#pragma unroll
            for (int mf = 0; mf < 4; mf++) {
                int gm = m0 + mh * 128 + wm * 64 + mf * 16 + quad * 4;
                int bb = gm >> 11;
                int srow = gm & (S_ - 1);
#pragma unroll
                for (int nh = 0; nh < 2; nh++)
#pragma unroll
                    for (int nf = 0; nf < 2; nf++) {
                        int colF = n0 + nh * 128 + wn * 32 + nf * 16 + lrow;
                        int head = colF >> 7, dcol = colF & 127;
                        float bv = bias[colF];
                        float vals[4];
#pragma unroll
                        for (int r = 0; r < 4; r++)
                            vals[r] = acc[mh * 4 + mf][nh * 2 + nf][r] + bv;
                        if (head < 34 && dcol < ROT_) {   // RoPE (uniform per quadrant)
                            int p = dcol >> 1;
                            float inv = exp2f(-(float)p * 0.41524101186092035f);
                            int odd = dcol & 1;
#pragma unroll
                            for (int r = 0; r < 4; r++) {
                                float partner = __shfl_xor(vals[r], 1);
                                float sn, cs;
                                __sincosf((float)(srow + r) * inv, &sn, &cs);
                                vals[r] = odd ? (vals[r] * cs + partner * sn)
                                              : (vals[r] * cs - partner * sn);
                            }
                        }
                        if (head < 32) {
                            unsigned short* dst =
                                Qb + ((size_t)(bb * NH_ + head) * S_ + srow) * HD_ + dcol;
#pragma unroll
                            for (int r = 0; r < 4; r++) dst[r * HD_] = f2bf(vals[r] * QSCALE);
                        } else if (head < 34) {
                            size_t base = ((size_t)(bb * NKV_ + head - 32) * S_ + srow) * HD_;
#pragma unroll
                            for (int r = 0; r < 4; r++)
                                Kb[base + r * HD_ + (((dcol >> 3) ^ ((srow + r) & 7)) << 3) +
                                   (dcol & 7)] = f2bf(vals[r]);
                        } else {
                            size_t base = ((size_t)(bb * NKV_ + head - 34) * HD_ + dcol) * S_;
#pragma unroll
                            for (int r = 0; r < 4; r++) {
                                int s = srow + r;
                                Vb[base + ((s >> 6) << 6) +
                                   ((((s >> 3) & 7) ^ (dcol & 7)) << 3) + (s & 7)] =
                                    f2bf(vals[r]);
                            }
                        }
                    }
            }
    }
}
#undef MMPH

// ---------------- flash attention v4: paired q-blocks for perfect balance ----
__global__ __launch_bounds__(256, 4) void flash4(const unsigned short* __restrict__ Qb,
                                                 const unsigned short* __restrict__ Kb,
                                                 const unsigned short* __restrict__ Vb,
                                                 unsigned short* __restrict__ ctxb) {
    int pair = blockIdx.x;              // 0..15
    int h = blockIdx.y, b = blockIdx.z;
    int tid = threadIdx.x, lane = tid & 63, wave = tid >> 6;
    int quad = lane >> 4, lrow = lane & 15;
    int bkvh = b * NKV_ + (h >> 4);
    int lw3 = lrow & 7;

    __shared__ __align__(16) unsigned short Ks[64 * 128];   // [key][swz d] 16KB
    __shared__ __align__(16) unsigned short Vt[128 * 64];   // [d][swz key] 16KB
    __shared__ __align__(16) unsigned short Ps[4][16 * 64]; // per-wave      8KB

    const unsigned short* Kg = Kb + (size_t)bkvh * S_ * HD_;
    const unsigned short* Vg = Vb + (size_t)bkvh * HD_ * S_;

#pragma unroll 1
    for (int u = 0; u < 2; u++) {
        int qblk = u ? ((int)(S_ / 64) - 1 - pair) : pair;
        int q0 = qblk * 64 + wave * 16;

        bf16x8 qf[4];
        {
            const unsigned short* qr =
                Qb + ((size_t)(b * NH_ + h) * S_ + q0 + lrow) * HD_ + quad * 8;
#pragma unroll
            for (int c = 0; c < 4; c++) qf[c] = *(const bf16x8*)(qr + c * 32);
        }

        float m_i[4], l_i[4];
        f32x4 oacc[8];
#pragma unroll
        for (int r = 0; r < 4; r++) { m_i[r] = -1e30f; l_i[r] = 0.f; }
#pragma unroll
        for (int t = 0; t < 8; t++) oacc[t] = (f32x4){0.f, 0.f, 0.f, 0.f};

        int nkt = qblk + 1;
#pragma unroll 1
        for (int kt = 0; kt < nkt; kt++) {
            int ks0 = kt * 64;
            {   // stage K
                const unsigned short* g =
                    Kg + (size_t)(ks0 + wave * 16 + (lane >> 4)) * HD_ + (lane & 15) * 8;
                unsigned short* l = &Ks[wave * 16 * 128];
#pragma unroll
                for (int i = 0; i < 4; i++)
                    gload_lds16(g + i * 4 * 128, l + i * 4 * 128);
            }
            {   // stage V
                const unsigned short* g =
                    Vg + (size_t)(wave * 32 + (lane >> 3)) * S_ + ks0 + (lane & 7) * 8;
                unsigned short* l = &Vt[wave * 32 * 64];
#pragma unroll
                for (int i = 0; i < 4; i++)
                    gload_lds16(g + (size_t)i * 8 * S_, l + i * 8 * 64);
            }
            __syncthreads();

            if (ks0 <= q0 + 15) {
                f32x4 s[4];
#pragma unroll
                for (int n = 0; n < 4; n++) s[n] = (f32x4){0.f, 0.f, 0.f, 0.f};
#pragma unroll
                for (int kc = 0; kc < 4; kc++)
#pragma unroll
                    for (int n = 0; n < 4; n++) {
                        bf16x8 kf = *(const bf16x8*)
                            &Ks[(n * 16 + lrow) * 128 + (((kc * 4 + quad) ^ lw3) << 3)];
                        s[n] = __builtin_amdgcn_mfma_f32_16x16x32_bf16(qf[kc], kf, s[n],
                                                                       0, 0, 0);
                    }
                if (kt == nkt - 1) {
#pragma unroll
                    for (int n = 0; n < 4; n++)
#pragma unroll
                        for (int r = 0; r < 4; r++)
                            if (ks0 + n * 16 + lrow > q0 + quad * 4 + r)
                                s[n][r] = -1e30f;
                }
                float alpha[4];
#pragma unroll
                for (int r = 0; r < 4; r++) {
                    float mx = fmaxf(fmaxf(s[0][r], s[1][r]), fmaxf(s[2][r], s[3][r]));
                    mx = fmaxf(mx, __shfl_xor(mx, 1));
                    mx = fmaxf(mx, __shfl_xor(mx, 2));
                    mx = fmaxf(mx, __shfl_xor(mx, 4));
                    mx = fmaxf(mx, __shfl_xor(mx, 8));
                    float mn = fmaxf(m_i[r], mx);
                    alpha[r] = exp2f(m_i[r] - mn);
                    m_i[r] = mn;
                    float rs = 0.f;
#pragma unroll
                    for (int n = 0; n < 4; n++) {
                        s[n][r] = exp2f(s[n][r] - mn);
                        rs += s[n][r];
                    }
                    rs += __shfl_xor(rs, 1);
                    rs += __shfl_xor(rs, 2);
                    rs += __shfl_xor(rs, 4);
                    rs += __shfl_xor(rs, 8);
                    l_i[r] = l_i[r] * alpha[r] + rs;
                }
#pragma unroll
                for (int n = 0; n < 4; n++)
#pragma unroll
                    for (int r = 0; r < 4; r++) {
                        int rw = quad * 4 + r, col = n * 16 + lrow;
                        Ps[wave][rw * 64 + (((col >> 3) ^ (rw & 7)) << 3) + (col & 7)] =
                            f2bf(s[n][r]);
                    }
#pragma unroll
                for (int t = 0; t < 8; t++)
#pragma unroll
                    for (int r = 0; r < 4; r++) oacc[t][r] *= alpha[r];
                bf16x8 pf0 = *(const bf16x8*)&Ps[wave][lrow * 64 + ((quad ^ lw3) << 3)];
                bf16x8 pf1 = *(const bf16x8*)&Ps[wave][lrow * 64 + (((4 + quad) ^ lw3) << 3)];
#pragma unroll
                for (int t = 0; t < 8; t++) {
                    int dim = t * 16 + lrow;
                    bf16x8 v0 = *(const bf16x8*)&Vt[dim * 64 + ((quad ^ lw3) << 3)];
                    bf16x8 v1 = *(const bf16x8*)&Vt[dim * 64 + (((4 + quad) ^ lw3) << 3)];
                    oacc[t] = __builtin_amdgcn_mfma_f32_16x16x32_bf16(pf0, v0, oacc[t], 0, 0, 0);
                    oacc[t] = __builtin_amdgcn_mfma_f32_16x16x32_bf16(pf1, v1, oacc[t], 0, 0, 0);
                }
            }
            __syncthreads();
        }
        float inv[4];
#pragma unroll
        for (int r = 0; r < 4; r++) inv[r] = 1.f / l_i[r];
#pragma unroll
        for (int t = 0; t < 8; t++)
#pragma unroll
            for (int r = 0; r < 4; r++) {
                int q = q0 + quad * 4 + r;
                ctxb[(size_t)(b * S_ + q) * (NH_ * HD_) + h * HD_ + t * 16 + lrow] =
                    f2bf(oacc[t][r] * inv[r]);
            }
    }
}

// ---------------- launch ----------------
extern "C" void kernel_launch(void* const* d_in, const int* in_sizes, int n_in,
                              void* d_out, int out_size, void* d_ws, size_t ws_size,
                              hipStream_t stream) {
    const float* hidden = (const float*)d_in[0];
    const float* Wqkv = (const float*)d_in[2];
    const float* bqkv = (const float*)d_in[3];
    const float* Wo   = (const float*)d_in[4];
    float* out = (float*)d_out;

    char* ws = (char*)d_ws;
    unsigned short* Xb    = (unsigned short*)ws;                         // 32 MB
    unsigned short* WqkvT = (unsigned short*)(ws + 33554432);            // 36 MB
    unsigned short* Qb    = (unsigned short*)(ws + 71303168);            // 32 MB
    unsigned short* Kb    = (unsigned short*)(ws + 104857600);           //  2 MB
    unsigned short* Vb    = (unsigned short*)(ws + 106954752);           //  2 MB
    unsigned short* ctxb  = (unsigned short*)(ws + 109051904);           // 32 MB
    unsigned short* WoT   = Xb;          // Xb dead after gemm_qkv

    // 1. hidden -> bf16
    convert_bf16<<<16384, 256, 0, stream>>>(hidden, Xb, (MROWS * H_) / 4);
    // 2. Wqkv [4096][4608] -> WqkvT bf16 [4608][4096]
    transpose_bf16<<<dim3(QKVD / 32, H_ / 32), 256, 0, stream>>>(Wqkv, WqkvT, H_, QKVD);
    // 3. QKV projection + bias + RoPE + pack (8-phase 256x256 core)
    gemm256<1, QKVD><<<dim3(QKVD / 256, MROWS / 256), 512, 131072, stream>>>(
        Xb, WqkvT, bqkv, nullptr, Qb, Kb, Vb);
    // 4. Wo -> WoT bf16 (into Xb region, dead after gemm_qkv)
    transpose_bf16<<<dim3(H_ / 32, H_ / 32), 256, 0, stream>>>(Wo, WoT, NH_ * HD_, H_);
    // 5. flash attention -> ctx bf16
    flash4<<<dim3(S_ / 128, NH_, B_), 256, 0, stream>>>(Qb, Kb, Vb, ctxb);
    // 6. output projection -> d_out fp32 (8-phase 256x256 core, 256-block grid)
    gemm256<0, H_><<<dim3(H_ / 256, MROWS / 256), 512, 131072, stream>>>(
        ctxb, WoT, nullptr, out, nullptr, nullptr, nullptr);
}